// Round 12
// baseline (383.768 us; speedup 1.0000x reference)
//
#include <hip/hip_runtime.h>
#include <math.h>

#define NN 50000
#define NE 800000
#define NG 64
#define D 128
#define IMG 4096
#define NT 30
#define CAP 48    // fixed per-node edge capacity; deg ~ Poisson(16), P(deg>48) ~ 1e-11/node
#define PART 196  // node partitions of 256 (50000>>8 = 195 max)
#define PCAP 6144 // records per partition region (mean 4081, sd 64 -> 32 sd headroom)
#define GSTRIDE 16  // gbase counters padded to one per 64B cacheline

#define PABLK ((NE + 1023) / 1024)          // 782 pass-A blocks, 4 edges/thread
#define PBLK ((NT * D + 2 * D * 64) / 256)  // 79 (exact)
#define AFBLK 64                            // A-fragment pre-pack blocks (16384 units)
#define GBLK ((NN + 63) / 64)               // 782
#define GEMM3A 390                          // gemm3 blocks for nodes [0, 24960)
#define GEMM3B (GBLK - GEMM3A)              // 392 blocks, nodes [24960, 50000)
#define AGGBLK ((NN + 7) / 8)               // 6250
#define AGGH (AGGBLK / 2)                   // 3125: half-split at node 25000
#define KSPLIT 16                           // img split-k slices of 256
#define IMGALL (64 * KSPLIT)                // 1024 img blocks
#define IREDBLK (64 * IMG / 256)            // 1024
#define SRCMASK 0x1FFFF                     // low 17 bits of record.x = src node

typedef unsigned int uint;
typedef unsigned short ushort;
typedef __attribute__((ext_vector_type(8))) __bf16 bf16x8;
typedef __attribute__((ext_vector_type(4))) float f32x4;

__device__ __forceinline__ uint bf16rne(float f) {
  uint h = __float_as_uint(f);
  return (h + 0x7fffu + ((h >> 16) & 1u)) >> 16;
}
__device__ __forceinline__ uint pack2bf(float a, float b) {
  return bf16rne(a) | (bf16rne(b) << 16);
}
__device__ __forceinline__ float bflo(uint u) { return __uint_as_float(u << 16); }
__device__ __forceinline__ float bfhi(uint u) { return __uint_as_float(u & 0xffff0000u); }

// X / xw bf16 storage: ROW-MAJOR, 64 uints (128 bf16) per node row.
// Edge records in ebuf: {src | type<<17, ew_bits}; padded slots {0,0} contribute 0.
// Bucket build: 2-pass LDS counting sort (pass A partition-scatter, pass B per-partition).
// Aggregation fetch (~87 MB) is STRUCTURAL cross-XCD replication (each XCD touches ~86%
// of the 12.8 MB row buffer; 8 x 11 MB = measured 87 MB); slicing/XCD-keying/nt-stores
// all null -> optimize schedule instead: agg2 split A/B, gemm3-A co-scheduled with
// agg2-B (MFMA rides in gather-idle pipes). gemm3 writes bufC (agg2-B still reads bufB).

#define AFPLANE 16384  // uint4 per h-plane: 16 by * 4 ss * 4 quad * 64 m

// ---------------- image GEMM body: xi = images @ W_img.T (split-k 16) ------------------

__device__ __forceinline__ void img_mfma_body(const uint4* __restrict__ AF,
                                              const float* __restrict__ W,
                                              float* __restrict__ splitbuf, int bx, int by) {
  int wv = threadIdx.x >> 6, lane = threadIdx.x & 63;
  int quad = lane >> 4;
  int n = bx * 64 + wv * 16 + (lane & 15);
  int k0 = by * 256;
  f32x4 acc[4] = {{0.f, 0.f, 0.f, 0.f}, {0.f, 0.f, 0.f, 0.f},
                  {0.f, 0.f, 0.f, 0.f}, {0.f, 0.f, 0.f, 0.f}};
  const float* wp = W + (size_t)n * IMG + k0 + quad * 16;
  const uint4* af0 = AF;
  const uint4* af1 = AF + AFPLANE;
  #pragma unroll
  for (int ss = 0; ss < 4; ss++) {
    float4 w0 = *(const float4*)(wp + ss * 64);
    float4 w1 = *(const float4*)(wp + ss * 64 + 4);
    float4 w2 = *(const float4*)(wp + ss * 64 + 8);
    float4 w3 = *(const float4*)(wp + ss * 64 + 12);
    union { uint4 u; bf16x8 v; } b1u, b2u;
    b1u.u.x = pack2bf(w0.x, w0.y);
    b1u.u.y = pack2bf(w0.z, w0.w);
    b1u.u.z = pack2bf(w1.x, w1.y);
    b1u.u.w = pack2bf(w1.z, w1.w);
    b2u.u.x = pack2bf(w2.x, w2.y);
    b2u.u.y = pack2bf(w2.z, w2.w);
    b2u.u.z = pack2bf(w3.x, w3.y);
    b2u.u.w = pack2bf(w3.z, w3.w);
    int base = ((by * 4 + ss) * 4 + quad) * 64 + (lane & 15);
    #pragma unroll
    for (int mt = 0; mt < 4; mt++) {
      union { uint4 u; bf16x8 v; } a1u, a2u;
      a1u.u = af0[base + mt * 16];
      a2u.u = af1[base + mt * 16];
      acc[mt] = __builtin_amdgcn_mfma_f32_16x16x32_bf16(a1u.v, b1u.v, acc[mt], 0, 0, 0);
      acc[mt] = __builtin_amdgcn_mfma_f32_16x16x32_bf16(a2u.v, b2u.v, acc[mt], 0, 0, 0);
    }
  }
  #pragma unroll
  for (int mt = 0; mt < 4; mt++)
    #pragma unroll
    for (int i = 0; i < 4; i++) {
      int m = mt * 16 + quad * 4 + i;
      splitbuf[((size_t)by * 64 + m) * IMG + n] = acc[mt][i];
    }
}

// ---------------- setup: pass-A partition scatter || prep || A-frag pack || goff --------

__global__ __launch_bounds__(256) void setup_fused(
    const int* __restrict__ row, const int* __restrict__ col,
    const float* __restrict__ ew, int* __restrict__ gbase, int2* __restrict__ pedge,
    const float* __restrict__ emb, const float* __restrict__ W1, float* __restrict__ embW,
    const float* __restrict__ W2, const float* __restrict__ W3,
    uint* __restrict__ Wbf2, uint* __restrict__ Wbf3,
    const float* __restrict__ images, uint4* __restrict__ AF,
    const int* __restrict__ batch, int* __restrict__ goff) {
  __shared__ int sh[2 * PART];  // hist | lbase
  int b = blockIdx.x;
  if (b < PABLK) {
    int* hist = sh;
    int* lbase = sh + PART;
    int t = threadIdx.x;
    for (int i = t; i < 2 * PART; i += 256) sh[i] = 0;
    __syncthreads();
    int e0 = b * 1024 + t * 4;
    int4 c4, r4;
    float4 w4;
    int pt0 = 0, pt1 = 0, pt2 = 0, pt3 = 0;
    int s0 = 0, s1 = 0, s2 = 0, s3 = 0;
    bool act = e0 < NE;  // NE % 4 == 0: active threads have full vectors
    if (act) {
      c4 = *(const int4*)(col + e0);
      r4 = *(const int4*)(row + e0);
      w4 = *(const float4*)(ew + e0);
      pt0 = c4.x >> 8; pt1 = c4.y >> 8; pt2 = c4.z >> 8; pt3 = c4.w >> 8;
      s0 = atomicAdd(&hist[pt0], 1);
      s1 = atomicAdd(&hist[pt1], 1);
      s2 = atomicAdd(&hist[pt2], 1);
      s3 = atomicAdd(&hist[pt3], 1);
    }
    __syncthreads();
    for (int i = t; i < PART; i += 256) {
      int c = hist[i];
      lbase[i] = c ? atomicAdd(&gbase[i * GSTRIDE], c) : 0;
    }
    __syncthreads();
    if (act) {
      int i0 = lbase[pt0] + s0;
      int i1 = lbase[pt1] + s1;
      int i2 = lbase[pt2] + s2;
      int i3 = lbase[pt3] + s3;
      if (i0 < PCAP)
        pedge[(size_t)pt0 * PCAP + i0] = make_int2(r4.x | ((c4.x & 255) << 17),
                                                   __float_as_int(w4.x));
      if (i1 < PCAP)
        pedge[(size_t)pt1 * PCAP + i1] = make_int2(r4.y | ((c4.y & 255) << 17),
                                                   __float_as_int(w4.y));
      if (i2 < PCAP)
        pedge[(size_t)pt2 * PCAP + i2] = make_int2(r4.z | ((c4.z & 255) << 17),
                                                   __float_as_int(w4.z));
      if (i3 < PCAP)
        pedge[(size_t)pt3 * PCAP + i3] = make_int2(r4.w | ((c4.w & 255) << 17),
                                                   __float_as_int(w4.w));
    }
  } else if (b < PABLK + PBLK) {
    int tid = (b - PABLK) * 256 + threadIdx.x;
    if (tid < NT * D) {
      // embW1 = emb @ W1^T (30x128)
      int tt = tid >> 7, nn2 = tid & 127;
      const float* ep = emb + (size_t)tt * D;
      const float* wp = W1 + (size_t)nn2 * D;
      float acc = 0.f;
      for (int k = 0; k < D; k += 4) {
        float4 evv = *(const float4*)(ep + k);
        float4 wvv = *(const float4*)(wp + k);
        acc += evv.x * wvv.x + evv.y * wvv.y + evv.z * wvv.z + evv.w * wvv.w;
      }
      embW[tid] = acc;
    } else if (tid < NT * D + D * 64) {
      int j = tid - NT * D;
      float2 v = ((const float2*)W2)[j];
      Wbf2[j] = pack2bf(v.x, v.y);
    } else {
      int j = tid - NT * D - D * 64;
      float2 v = ((const float2*)W3)[j];
      Wbf3[j] = pack2bf(v.x, v.y);
    }
  } else if (b < PABLK + PBLK + AFBLK) {
    // A-fragment pre-pack: AF[h][(by*4+ss)*4+quad][m] = bf16x8 of images[m][g*16+8h..]
    int tid2 = (b - PABLK - PBLK) * 256 + threadIdx.x;  // 0..16383
    int m = tid2 & 63;
    int oo = tid2 >> 6;  // (by*4+ss)*4+quad
    int quad = oo & 3, ss = (oo >> 2) & 3, byy = oo >> 4;
    int k = (byy * 16 + ss * 4 + quad) << 4;
    const float* ap = images + (size_t)m * IMG + k;
    float4 a0_ = *(const float4*)(ap);
    float4 a1_ = *(const float4*)(ap + 4);
    float4 a2_ = *(const float4*)(ap + 8);
    float4 a3_ = *(const float4*)(ap + 12);
    uint4 h0, h1;
    h0.x = pack2bf(a0_.x, a0_.y);
    h0.y = pack2bf(a0_.z, a0_.w);
    h0.z = pack2bf(a1_.x, a1_.y);
    h0.w = pack2bf(a1_.z, a1_.w);
    h1.x = pack2bf(a2_.x, a2_.y);
    h1.y = pack2bf(a2_.z, a2_.w);
    h1.z = pack2bf(a3_.x, a3_.y);
    h1.w = pack2bf(a3_.z, a3_.w);
    AF[tid2] = h0;
    AF[AFPLANE + tid2] = h1;
  } else {
    int g = threadIdx.x;
    if (g <= NG) {
      int lo = 0, hi = NN;
      while (lo < hi) {
        int mid = (lo + hi) >> 1;
        if (batch[mid] < g) lo = mid + 1; else hi = mid;
      }
      goff[g] = lo;
    }
  }
}

// ---------------- img GEMM (long blocks first) || pass-B bucket build -------------------

__global__ __launch_bounds__(256) void bucket_plus_img(const int* __restrict__ gbase,
                                                       const int2* __restrict__ pedge,
                                                       const int* __restrict__ types,
                                                       int2* __restrict__ ebuf,
                                                       int* __restrict__ cnt,
                                                       float* __restrict__ dis,
                                                       const uint4* __restrict__ AF,
                                                       const float* __restrict__ Wimg,
                                                       float* __restrict__ splitbuf) {
  __shared__ int lcnt[256];
  __shared__ float ldeg[256];
  int b = blockIdx.x;
  if (b < IMGALL) {
    img_mfma_body(AF, Wimg, splitbuf, b & 63, b >> 6);
  } else {
    int t = threadIdx.x;
    lcnt[t] = 0;
    ldeg[t] = 0.f;
    __syncthreads();
    int p = b - IMGALL;
    int total = min(gbase[p * GSTRIDE], PCAP);
    const int2* src = pedge + (size_t)p * PCAP;
    for (int i = t; i < total; i += 256) {
      int2 rec = src[i];
      int nl = (rec.x >> 17) & 255;
      int sv = rec.x & SRCMASK;
      int s = atomicAdd(&lcnt[nl], 1);
      atomicAdd(&ldeg[nl], __int_as_float(rec.y));
      if (s < CAP)
        ebuf[(size_t)(p * 256 + nl) * CAP + s] = make_int2(sv | (types[sv] << 17), rec.y);
    }
    __syncthreads();
    int node = p * 256 + t;
    if (node < NN) {
      cnt[node] = lcnt[t];
      dis[node] = 1.0f / sqrtf(ldeg[t] + 1.0f);
    }
  }
}

// ---------------- layer 1: X1 = relu(sum_e norm*embW[type[src]] + dis^2*embW[type] + b1) --

__global__ __launch_bounds__(512) void lay1_fused(const int* __restrict__ cnt,
                                                  const int2* __restrict__ ebuf,
                                                  const float* __restrict__ dis,
                                                  const int* __restrict__ types,
                                                  const float* __restrict__ embW,
                                                  const float* __restrict__ b1,
                                                  uint* __restrict__ outbf) {
  __shared__ float sE[NT * D];  // 15360 floats
  __shared__ float sB[D];
  int t = threadIdx.x;
  for (int i = t; i < NT * D; i += 512) sE[i] = embW[i];
  if (t < D) sB[t] = b1[t];
  __syncthreads();
  int wave = t >> 6, lane = t & 63;
  #pragma unroll
  for (int r = 0; r < 4; r++) {
    int node = blockIdx.x * 32 + wave * 4 + r;
    if (node >= NN) continue;
    float ax = sB[2 * lane], ay = sB[2 * lane + 1];
    int n = min(cnt[node], CAP);
    int nc = (n + 7) >> 3;
    const int2* eb = ebuf + (size_t)node * CAP;
    float disc = dis[node];
    for (int c = 0; c < nc; c++) {
      const int2* ep = eb + (c << 3);
      int4 q0 = *(const int4*)(ep + 0);
      int4 q1 = *(const int4*)(ep + 2);
      int4 q2 = *(const int4*)(ep + 4);
      int4 q3 = *(const int4*)(ep + 6);
      int t0 = q0.x >> 17, t1 = q0.z >> 17, t2 = q1.x >> 17, t3 = q1.z >> 17;
      int t4 = q2.x >> 17, t5 = q2.z >> 17, t6 = q3.x >> 17, t7 = q3.z >> 17;
      float m0 = dis[q0.x & SRCMASK] * __int_as_float(q0.y) * disc;
      float m1 = dis[q0.z & SRCMASK] * __int_as_float(q0.w) * disc;
      float m2 = dis[q1.x & SRCMASK] * __int_as_float(q1.y) * disc;
      float m3 = dis[q1.z & SRCMASK] * __int_as_float(q1.w) * disc;
      float m4 = dis[q2.x & SRCMASK] * __int_as_float(q2.y) * disc;
      float m5 = dis[q2.z & SRCMASK] * __int_as_float(q2.w) * disc;
      float m6 = dis[q3.x & SRCMASK] * __int_as_float(q3.y) * disc;
      float m7 = dis[q3.z & SRCMASK] * __int_as_float(q3.w) * disc;
      float2 e0 = *(const float2*)&sE[t0 * D + 2 * lane];
      float2 e1 = *(const float2*)&sE[t1 * D + 2 * lane];
      float2 e2 = *(const float2*)&sE[t2 * D + 2 * lane];
      float2 e3 = *(const float2*)&sE[t3 * D + 2 * lane];
      float2 e4 = *(const float2*)&sE[t4 * D + 2 * lane];
      float2 e5 = *(const float2*)&sE[t5 * D + 2 * lane];
      float2 e6 = *(const float2*)&sE[t6 * D + 2 * lane];
      float2 e7 = *(const float2*)&sE[t7 * D + 2 * lane];
      ax = fmaf(m0, e0.x, ax); ay = fmaf(m0, e0.y, ay);
      ax = fmaf(m1, e1.x, ax); ay = fmaf(m1, e1.y, ay);
      ax = fmaf(m2, e2.x, ax); ay = fmaf(m2, e2.y, ay);
      ax = fmaf(m3, e3.x, ax); ay = fmaf(m3, e3.y, ay);
      ax = fmaf(m4, e4.x, ax); ay = fmaf(m4, e4.y, ay);
      ax = fmaf(m5, e5.x, ax); ay = fmaf(m5, e5.y, ay);
      ax = fmaf(m6, e6.x, ax); ay = fmaf(m6, e6.y, ay);
      ax = fmaf(m7, e7.x, ax); ay = fmaf(m7, e7.y, ay);
    }
    float dd = disc * disc;
    float2 es = *(const float2*)&sE[types[node] * D + 2 * lane];
    ax = fmaf(dd, es.x, ax);
    ay = fmaf(dd, es.y, ay);
    ax = fmaxf(ax, 0.f);
    ay = fmaxf(ay, 0.f);
    outbf[(size_t)node * 64 + lane] = pack2bf(ax, ay);
  }
}

// ---------------- node GEMM via MFMA: xw = X @ W^T (bf16 row-major in/out) ----------------

__device__ __forceinline__ void node_gemm_body(const uint* __restrict__ Abf,
                                               const uint* __restrict__ Wbf,
                                               uint* __restrict__ outbf, int bx,
                                               ushort* __restrict__ tile) {
  int w = threadIdx.x >> 6, lane = threadIdx.x & 63;
  int quad = lane >> 4;
  int m0 = bx * 64 + w * 16;
  int mrow = m0 + (lane & 15);
  int arow = (mrow < NN) ? mrow : 0;
  uint4 afr[4];
  #pragma unroll
  for (int ks = 0; ks < 4; ks++)
    afr[ks] = *(const uint4*)(Abf + (size_t)arow * 64 + ks * 16 + quad * 4);
  f32x4 acc[8] = {};
  #pragma unroll
  for (int nt = 0; nt < 8; nt++) {
    int n = nt * 16 + (lane & 15);
    #pragma unroll
    for (int ks = 0; ks < 4; ks++) {
      union { uint4 u; bf16x8 v; } au, bu;
      au.u = afr[ks];
      bu.u = *(const uint4*)(Wbf + (size_t)n * 64 + ks * 16 + quad * 4);
      acc[nt] = __builtin_amdgcn_mfma_f32_16x16x32_bf16(au.v, bu.v, acc[nt], 0, 0, 0);
    }
  }
  ushort* tw = tile + w * 16 * 136;
  #pragma unroll
  for (int nt = 0; nt < 8; nt++)
    #pragma unroll
    for (int i = 0; i < 4; i++)
      tw[(quad * 4 + i) * 136 + nt * 16 + (lane & 15)] = (ushort)bf16rne(acc[nt][i]);
  __builtin_amdgcn_s_waitcnt(0);  // wave-local LDS ordering (per-wave tile)
  #pragma unroll
  for (int rep = 0; rep < 4; rep++) {
    int r = rep * 4 + quad;
    int j = lane & 15;
    int node = m0 + r;
    if (node < NN) {
      uint4 v = *(const uint4*)&tw[r * 136 + j * 8];
      *(uint4*)(outbf + (size_t)node * 64 + j * 4) = v;
    }
  }
}

// ---------------- aggregation body: 2 nodes/wave, dense 16-edge chunks -------------------

#define GA(k, s_) uint2 u##k = xw2[(size_t)(s_) * 32 + fl];
#define FA(k, m_) a0 = fmaf(m_, bflo(u##k.x), a0); a1 = fmaf(m_, bfhi(u##k.x), a1); \
                  a2 = fmaf(m_, bflo(u##k.y), a2); a3 = fmaf(m_, bfhi(u##k.y), a3);

__device__ __forceinline__ void aggregate2_body(const uint* __restrict__ xw,
                                                const int* __restrict__ cnt,
                                                const int2* __restrict__ ebuf,
                                                const float* __restrict__ dis,
                                                const float* __restrict__ bias, int relu,
                                                uint* __restrict__ outbf, int blk) {
  const uint2* xw2 = (const uint2*)xw;
  int wave = threadIdx.x >> 6;
  int lane = threadIdx.x & 63;
  int half = lane >> 5;
  int fl = lane & 31;  // uint2 index within row
  int node = (blk * 4 + wave) * 2 + half;
  if (node >= NN) return;
  float a0 = 0.f, a1 = 0.f, a2 = 0.f, a3 = 0.f;
  int n = min(cnt[node], CAP);
  int nc = (n + 15) >> 4;  // dense 16-edge chunks (CAP = 48 = 3*16)
  const int2* eb = ebuf + (size_t)node * CAP;
  float disc = dis[node];
  for (int c = 0; c < nc; c++) {
    const int2* ep = eb + (c << 4);
    int4 r0 = *(const int4*)(ep + 0);
    int4 r1 = *(const int4*)(ep + 2);
    int4 r2 = *(const int4*)(ep + 4);
    int4 r3 = *(const int4*)(ep + 6);
    int4 r4 = *(const int4*)(ep + 8);
    int4 r5 = *(const int4*)(ep + 10);
    int4 r6 = *(const int4*)(ep + 12);
    int4 r7 = *(const int4*)(ep + 14);
    int s0 = r0.x & SRCMASK, s1 = r0.z & SRCMASK, s2 = r1.x & SRCMASK, s3 = r1.z & SRCMASK;
    int s4 = r2.x & SRCMASK, s5 = r2.z & SRCMASK, s6 = r3.x & SRCMASK, s7 = r3.z & SRCMASK;
    int s8 = r4.x & SRCMASK, s9 = r4.z & SRCMASK, s10 = r5.x & SRCMASK, s11 = r5.z & SRCMASK;
    int s12 = r6.x & SRCMASK, s13 = r6.z & SRCMASK, s14 = r7.x & SRCMASK, s15 = r7.z & SRCMASK;
    GA(0, s0)  GA(1, s1)  GA(2, s2)  GA(3, s3)
    GA(4, s4)  GA(5, s5)  GA(6, s6)  GA(7, s7)
    GA(8, s8)  GA(9, s9)  GA(10, s10) GA(11, s11)
    GA(12, s12) GA(13, s13) GA(14, s14) GA(15, s15)
    float m0 = dis[s0] * __int_as_float(r0.y) * disc;
    float m1 = dis[s1] * __int_as_float(r0.w) * disc;
    float m2 = dis[s2] * __int_as_float(r1.y) * disc;
    float m3 = dis[s3] * __int_as_float(r1.w) * disc;
    float m4 = dis[s4] * __int_as_float(r2.y) * disc;
    float m5 = dis[s5] * __int_as_float(r2.w) * disc;
    float m6 = dis[s6] * __int_as_float(r3.y) * disc;
    float m7 = dis[s7] * __int_as_float(r3.w) * disc;
    float m8 = dis[s8] * __int_as_float(r4.y) * disc;
    float m9 = dis[s9] * __int_as_float(r4.w) * disc;
    float m10 = dis[s10] * __int_as_float(r5.y) * disc;
    float m11 = dis[s11] * __int_as_float(r5.w) * disc;
    float m12 = dis[s12] * __int_as_float(r6.y) * disc;
    float m13 = dis[s13] * __int_as_float(r6.w) * disc;
    float m14 = dis[s14] * __int_as_float(r7.y) * disc;
    float m15 = dis[s15] * __int_as_float(r7.w) * disc;
    FA(0, m0)  FA(1, m1)  FA(2, m2)  FA(3, m3)
    FA(4, m4)  FA(5, m5)  FA(6, m6)  FA(7, m7)
    FA(8, m8)  FA(9, m9)  FA(10, m10) FA(11, m11)
    FA(12, m12) FA(13, m13) FA(14, m14) FA(15, m15)
  }
  // self-loop
  float dd = disc * disc;
  {
    uint2 u = xw2[(size_t)node * 32 + fl];
    a0 = fmaf(dd, bflo(u.x), a0);
    a1 = fmaf(dd, bfhi(u.x), a1);
    a2 = fmaf(dd, bflo(u.y), a2);
    a3 = fmaf(dd, bfhi(u.y), a3);
  }
  float4 b = *(const float4*)(bias + 4 * fl);
  a0 += b.x; a1 += b.y; a2 += b.z; a3 += b.w;
  if (relu) {
    a0 = fmaxf(a0, 0.f);
    a1 = fmaxf(a1, 0.f);
    a2 = fmaxf(a2, 0.f);
    a3 = fmaxf(a3, 0.f);
  }
  uint2 o;
  o.x = pack2bf(a0, a1);
  o.y = pack2bf(a2, a3);
  ((uint2*)outbf)[(size_t)node * 32 + fl] = o;
}

// aggregate with block offset (half-splits share this)
__global__ __launch_bounds__(256) void aggregate2(const uint* __restrict__ xw,
                                                  const int* __restrict__ cnt,
                                                  const int2* __restrict__ ebuf,
                                                  const float* __restrict__ dis,
                                                  const float* __restrict__ bias, int relu,
                                                  uint* __restrict__ outbf, int blkoff) {
  aggregate2_body(xw, cnt, ebuf, dis, bias, relu, outbf, blockIdx.x + blkoff);
}

// ---------------- small-M GEMM body: bias folded into by==0; out pre-zeroed ------------

__device__ __forceinline__ void gemm64_body(const float* __restrict__ A, int lda,
                                            const float* __restrict__ W,
                                            const float* __restrict__ bias,
                                            float* __restrict__ out, int N, int K,
                                            int kChunk, int bx, int by,
                                            float (*xs)[68], float (*ws)[68]) {
  int t = threadIdx.x;
  int n0 = bx * 64;
  int k0 = by * kChunk;
  int kEnd = min(K, k0 + kChunk);
  int tn = t & 15;
  int tm = t >> 4;
  float acc[4][4] = {};
  if (by == 0) {
    #pragma unroll
    for (int ni = 0; ni < 4; ni++) {
      float bv = bias[n0 + tn * 4 + ni];
      #pragma unroll
      for (int mi = 0; mi < 4; mi++) acc[mi][ni] = bv;
    }
  }
  for (int kt = k0; kt < kEnd; kt += 16) {
    int kc = (t & 3) * 4;
    int rr = t >> 2;
    float4 va = *(const float4*)(A + (size_t)rr * lda + kt + kc);
    xs[kc + 0][rr] = va.x; xs[kc + 1][rr] = va.y; xs[kc + 2][rr] = va.z; xs[kc + 3][rr] = va.w;
    float4 vw = *(const float4*)(W + (size_t)(n0 + rr) * K + kt + kc);
    ws[kc + 0][rr] = vw.x; ws[kc + 1][rr] = vw.y; ws[kc + 2][rr] = vw.z; ws[kc + 3][rr] = vw.w;
    __syncthreads();
    #pragma unroll
    for (int k = 0; k < 16; k++) {
      float4 xv = *(const float4*)&xs[k][tm * 4];
      float4 wv = *(const float4*)&ws[k][tn * 4];
      float xm[4] = {xv.x, xv.y, xv.z, xv.w};
      float wn[4] = {wv.x, wv.y, wv.z, wv.w};
      #pragma unroll
      for (int mi = 0; mi < 4; mi++)
        #pragma unroll
        for (int ni = 0; ni < 4; ni++)
          acc[mi][ni] = fmaf(xm[mi], wn[ni], acc[mi][ni]);
    }
    __syncthreads();
  }
  #pragma unroll
  for (int mi = 0; mi < 4; mi++)
    #pragma unroll
    for (int ni = 0; ni < 4; ni++)
      atomicAdd(&out[(size_t)(tm * 4 + mi) * N + n0 + tn * 4 + ni], acc[mi][ni]);
}

// fused: img split-k reduce -> xcat (first) || node GEMM (W2)
__global__ __launch_bounds__(256) void gemm2_plus_imgred(const uint* __restrict__ bufX,
                                                         const uint* __restrict__ wbf2,
                                                         uint* __restrict__ bufB,
                                                         const float* __restrict__ splitbuf,
                                                         const float* __restrict__ b_img,
                                                         float* __restrict__ xcat) {
  __shared__ ushort tile[4 * 16 * 136];
  int b = blockIdx.x;
  if (b < IREDBLK) {
    int idx = b * 256 + threadIdx.x;
    float acc = b_img[idx & (IMG - 1)];
    #pragma unroll
    for (int s = 0; s < KSPLIT; s++) acc += splitbuf[(size_t)s * 64 * IMG + idx];
    xcat[(size_t)(idx >> 12) * (IMG + D) + (idx & (IMG - 1))] = acc;
  } else {
    node_gemm_body(bufX, wbf2, bufB, b - IREDBLK, tile);
  }
}

// pipeline: gemm3 A-half (nodes < 24960, reads bufX written by agg2-A) || agg2 B-half.
// gemm3 writes bufC: agg2-B still gathers from bufB, so bufB must stay intact.
__global__ __launch_bounds__(256) void gemm3a_agg2b(const uint* __restrict__ bufX,
                                                    const uint* __restrict__ wbf3,
                                                    uint* __restrict__ bufC,
                                                    const uint* __restrict__ bufB,
                                                    const int* __restrict__ cnt,
                                                    const int2* __restrict__ ebuf,
                                                    const float* __restrict__ dis,
                                                    const float* __restrict__ b2) {
  __shared__ ushort tile[4 * 16 * 136];
  int b = blockIdx.x;
  if (b < GEMM3A) {
    node_gemm_body(bufX, wbf3, bufC, b, tile);
  } else {
    aggregate2_body(bufB, cnt, ebuf, dis, b2, 1, (uint*)bufX, (b - GEMM3A) + AGGH);
  }
}

// gemm3 B-half || oi-GEMM || oc-main (both need only xcat-xi, ready since imgred)
__global__ __launch_bounds__(256) void gemm3b_oi_oc(const uint* __restrict__ bufX,
                                                    const uint* __restrict__ wbf3,
                                                    uint* __restrict__ bufC,
                                                    const float* __restrict__ xcat,
                                                    const float* __restrict__ Wi,
                                                    const float* __restrict__ bi,
                                                    float* __restrict__ oi_raw,
                                                    const float* __restrict__ Wc,
                                                    const float* __restrict__ bc,
                                                    float* __restrict__ oc_raw) {
  __shared__ __align__(16) char smem[4 * 16 * 136 * 2];  // 17408 B, aliased
  int b = blockIdx.x;
  if (b < GEMM3B) {
    node_gemm_body(bufX, wbf3, bufC, GEMM3A + b, (ushort*)smem);
  } else if (b < GEMM3B + 64) {
    int j = b - GEMM3B;
    float (*xs)[68] = (float(*)[68])smem;
    float (*ws)[68] = (float(*)[68])(smem + 16 * 68 * 4);
    gemm64_body(xcat, IMG + D, Wi, bi, oi_raw, D, IMG, 128, j & 1, j >> 1, xs, ws);
  } else {
    int j = b - GEMM3B - 64;
    float (*xs)[68] = (float(*)[68])smem;
    float (*ws)[68] = (float(*)[68])(smem + 16 * 68 * 4);
    gemm64_body(xcat, IMG + D, Wc, bc, oc_raw, D, IMG + D, 128, j & 1, j >> 1, xs, ws);
  }
}

// ---------------- pooling: scaled atomicAdd into xcat (32 chunks/graph) ----------------

__global__ __launch_bounds__(64) void pool_bf(const uint* __restrict__ xb,
                                              const int* __restrict__ goff,
                                              float* __restrict__ xcat) {
  int g = blockIdx.x >> 5;
  int chunk = blockIdx.x & 31;
  int fl = threadIdx.x;  // uint index within row
  int s = goff[g], e = goff[g + 1];
  float inv = 1.0f / fmaxf((float)(e - s), 1.0f);
  float ax = 0.f, ay = 0.f;
  for (int i = s + chunk; i < e; i += 32) {
    uint u = xb[(size_t)i * 64 + fl];
    ax += bflo(u);
    ay += bfhi(u);
  }
  atomicAdd(&xcat[(size_t)g * (IMG + D) + IMG + 2 * fl], ax * inv);
  atomicAdd(&xcat[(size_t)g * (IMG + D) + IMG + 2 * fl + 1], ay * inv);
}

// oc-GEMM tail: k in [4096, 4224) (pooled region), after pool
__global__ __launch_bounds__(256) void oc_tail(const float* __restrict__ xcat,
                                               const float* __restrict__ Wc,
                                               const float* __restrict__ bc,
                                               float* __restrict__ oc_raw) {
  __shared__ float xs[16][68];
  __shared__ float ws[16][68];
  gemm64_body(xcat, IMG + D, Wc, bc, oc_raw, D, IMG + D, 4096, blockIdx.x, 1, xs, ws);
}

__global__ __launch_bounds__(128) void normalize_rows(const float* __restrict__ oi_raw,
                                                      const float* __restrict__ oc_raw,
                                                      float* __restrict__ out) {
  int r = blockIdx.x;
  int t = threadIdx.x;
  const float* src = (r < 64) ? (oi_raw + r * D) : (oc_raw + (r - 64) * D);
  float v = src[t];
  __shared__ float red[128];
  red[t] = v * v;
  __syncthreads();
  for (int s = 64; s > 0; s >>= 1) {
    if (t < s) red[t] += red[t + s];
    __syncthreads();
  }
  out[r * D + t] = v / sqrtf(red[0]);
}

// ---------------- launch ----------------

extern "C" void kernel_launch(void* const* d_in, const int* in_sizes, int n_in,
                              void* d_out, int out_size, void* d_ws, size_t ws_size,
                              hipStream_t stream) {
  const float* images = (const float*)d_in[0];
  const int* node_types = (const int*)d_in[1];
  const int* erow = (const int*)d_in[2];
  const int* ecol = erow + NE;
  const float* eattr = (const float*)d_in[3];
  const int* batch = (const int*)d_in[4];
  const float* emb = (const float*)d_in[5];
  const float* W_img = (const float*)d_in[6];
  const float* b_img = (const float*)d_in[7];
  const float* W1 = (const float*)d_in[8];
  const float* b1 = (const float*)d_in[9];
  const float* W2 = (const float*)d_in[10];
  const float* b2 = (const float*)d_in[11];
  const float* W3 = (const float*)d_in[12];
  const float* b3 = (const float*)d_in[13];
  const float* Wi = (const float*)d_in[14];
  const float* bi = (const float*)d_in[15];
  const float* Wc = (const float*)d_in[16];
  const float* bc = (const float*)d_in[17];
  float* out = (float*)d_out;

  char* w = (char*)d_ws;
  auto alloc = [&](size_t bytes) -> void* {
    void* p = (void*)w;
    w += (bytes + 511) & ~(size_t)511;
    return p;
  };
  // zeroed region first: gbase(padded) + xcat + oi_raw + oc_raw + ebuf (~20.4 MB)
  int* gbase = (int*)alloc((size_t)PART * GSTRIDE * 4);  // 1 counter / 64B line
  float* xcat = (float*)alloc((size_t)64 * (IMG + D) * 4);
  float* oi_raw = (float*)alloc(64 * D * 4);
  float* oc_raw = (float*)alloc(64 * D * 4);
  int2* ebuf = (int2*)alloc((size_t)NN * CAP * 8);  // 19.2 MB zero-padded buckets
  size_t zero_bytes = (size_t)(w - (char*)d_ws);
  int* cnt = (int*)alloc((size_t)NN * 4);  // fully written by bucket_build
  int* goff = (int*)alloc((NG + 1) * 4);
  float* dis = (float*)alloc(NN * 4);
  float* embW1 = (float*)alloc(NT * D * 4);
  uint* wbf2 = (uint*)alloc(D * 64 * 4);
  uint* wbf3 = (uint*)alloc(D * 64 * 4);
  int2* pedge = (int2*)alloc((size_t)PART * PCAP * 8);  // 9.6 MB partition regions
  uint4* AF = (uint4*)alloc((size_t)2 * AFPLANE * 16);  // 512 KB A fragments
  uint* bufX = (uint*)alloc((size_t)NN * D * 2);  // X bf16 rows
  uint* bufB = (uint*)alloc((size_t)NN * D * 2);  // xw bf16 rows (layer-2 GEMM out)
  uint* bufC = (uint*)alloc((size_t)NN * D * 2);  // xw bf16 rows (layer-3 GEMM out)
  float* splitbuf = (float*)alloc((size_t)KSPLIT * 64 * IMG * 4);

  hipMemsetAsync(d_ws, 0, zero_bytes, stream);

  // pass-A partition scatter || prep || A-fragment pack || graph bounds
  setup_fused<<<PABLK + PBLK + AFBLK + 1, 256, 0, stream>>>(
      erow, ecol, eattr, gbase, pedge, emb, W1, embW1, W2, W3, wbf2, wbf3,
      images, AF, batch, goff);
  // img GEMM (16 k-slices, long blocks first) || pass-B bucket build
  bucket_plus_img<<<IMGALL + PART, 256, 0, stream>>>(gbase, pedge, node_types, ebuf,
                                                     cnt, dis, AF, W_img, splitbuf);
  // layer 1 (type-collapsed aggregation)
  lay1_fused<<<(NN + 31) / 32, 512, 0, stream>>>(cnt, ebuf, dis, node_types, embW1, b1, bufX);
  // img split-k reduce into xcat (first) || node GEMM W2
  gemm2_plus_imgred<<<IREDBLK + GBLK, 256, 0, stream>>>(bufX, wbf2, bufB, splitbuf, b_img,
                                                        xcat);
  // aggregate layer 2, A-half (nodes [0, 25000))
  aggregate2<<<AGGH, 256, 0, stream>>>(bufB, cnt, ebuf, dis, b2, 1, bufX, 0);
  // gemm3 A-half (nodes < 24960, from agg2-A output) || aggregate layer 2 B-half
  gemm3a_agg2b<<<GEMM3A + AGGH, 256, 0, stream>>>(bufX, wbf3, bufC, bufB, cnt, ebuf,
                                                  dis, b2);
  // gemm3 B-half || oi-GEMM || oc-main (xi-only parts)
  gemm3b_oi_oc<<<GEMM3B + 128, 256, 0, stream>>>(bufX, wbf3, bufC, xcat, Wi, bi, oi_raw,
                                                 Wc, bc, oc_raw);
  // aggregate layer 3 (no relu): bufC -> bufX
  aggregate2<<<AGGBLK, 256, 0, stream>>>(bufC, cnt, ebuf, dis, b3, 0, bufX, 0);
  // mean-pool into xcat
  pool_bf<<<NG * 32, 64, 0, stream>>>(bufX, goff, xcat);
  // oc tail: k in [4096, 4224)
  oc_tail<<<2, 256, 0, stream>>>(xcat, Wc, bc, oc_raw);
  // row-normalize both heads
  normalize_rows<<<128, 128, 0, stream>>>(oi_raw, oc_raw, out);
}

// Round 13
// 378.529 us; speedup vs baseline: 1.0138x; 1.0138x over previous
//
#include <hip/hip_runtime.h>
#include <math.h>

#define NN 50000
#define NE 800000
#define NG 64
#define D 128
#define IMG 4096
#define NT 30
#define CAP 48    // fixed per-node edge capacity; deg ~ Poisson(16), P(deg>48) ~ 1e-11/node
#define PART 196  // node partitions of 256 (50000>>8 = 195 max)
#define PCAP 6144 // records per partition region (mean 4081, sd 64 -> 32 sd headroom)
#define GSTRIDE 16  // gbase counters padded to one per 64B cacheline

#define PABLK ((NE + 1023) / 1024)          // 782 pass-A blocks, 4 edges/thread
#define PBLK ((NT * D + 2 * D * 64) / 256)  // 79 (exact)
#define AFBLK 64                            // A-fragment pre-pack blocks (16384 units)
#define GBLK ((NN + 63) / 64)               // 782
#define AGGBLK ((NN + 7) / 8)               // 6250
#define KSPLIT 16                           // img split-k slices of 256
#define IMGALL (64 * KSPLIT)                // 1024 img blocks
#define IREDBLK (64 * IMG / 256)            // 1024
#define SRCMASK 0x1FFFF                     // low 17 bits of record.x = src node

typedef unsigned int uint;
typedef unsigned short ushort;
typedef __attribute__((ext_vector_type(8))) __bf16 bf16x8;
typedef __attribute__((ext_vector_type(4))) float f32x4;

__device__ __forceinline__ uint bf16rne(float f) {
  uint h = __float_as_uint(f);
  return (h + 0x7fffu + ((h >> 16) & 1u)) >> 16;
}
__device__ __forceinline__ uint pack2bf(float a, float b) {
  return bf16rne(a) | (bf16rne(b) << 16);
}
__device__ __forceinline__ float bflo(uint u) { return __uint_as_float(u << 16); }
__device__ __forceinline__ float bfhi(uint u) { return __uint_as_float(u & 0xffff0000u); }

// X / xw bf16 storage: ROW-MAJOR, 64 uints (128 bf16) per node row.
// Edge records in ebuf: {src | type<<17, ew_bits}; padded slots {0,0} contribute 0.
// Bucket build: 2-pass LDS counting sort (pass A partition-scatter, pass B per-partition).
// Aggregation fetch (~87 MB @ ~2.2 TB/s) is the STRUCTURAL cross-XCD replication floor:
// slicing (r9: +43MB), XCD-keying (r9: null), nt-stores (r11: null), agg/gemm
// co-scheduling (r12: null) all failed to move it. This file = r8 best (379 us).

#define AFPLANE 16384  // uint4 per h-plane: 16 by * 4 ss * 4 quad * 64 m

// ---------------- image GEMM body: xi = images @ W_img.T (split-k 16) ------------------

__device__ __forceinline__ void img_mfma_body(const uint4* __restrict__ AF,
                                              const float* __restrict__ W,
                                              float* __restrict__ splitbuf, int bx, int by) {
  int wv = threadIdx.x >> 6, lane = threadIdx.x & 63;
  int quad = lane >> 4;
  int n = bx * 64 + wv * 16 + (lane & 15);
  int k0 = by * 256;
  f32x4 acc[4] = {{0.f, 0.f, 0.f, 0.f}, {0.f, 0.f, 0.f, 0.f},
                  {0.f, 0.f, 0.f, 0.f}, {0.f, 0.f, 0.f, 0.f}};
  const float* wp = W + (size_t)n * IMG + k0 + quad * 16;
  const uint4* af0 = AF;
  const uint4* af1 = AF + AFPLANE;
  #pragma unroll
  for (int ss = 0; ss < 4; ss++) {
    float4 w0 = *(const float4*)(wp + ss * 64);
    float4 w1 = *(const float4*)(wp + ss * 64 + 4);
    float4 w2 = *(const float4*)(wp + ss * 64 + 8);
    float4 w3 = *(const float4*)(wp + ss * 64 + 12);
    union { uint4 u; bf16x8 v; } b1u, b2u;
    b1u.u.x = pack2bf(w0.x, w0.y);
    b1u.u.y = pack2bf(w0.z, w0.w);
    b1u.u.z = pack2bf(w1.x, w1.y);
    b1u.u.w = pack2bf(w1.z, w1.w);
    b2u.u.x = pack2bf(w2.x, w2.y);
    b2u.u.y = pack2bf(w2.z, w2.w);
    b2u.u.z = pack2bf(w3.x, w3.y);
    b2u.u.w = pack2bf(w3.z, w3.w);
    int base = ((by * 4 + ss) * 4 + quad) * 64 + (lane & 15);
    #pragma unroll
    for (int mt = 0; mt < 4; mt++) {
      union { uint4 u; bf16x8 v; } a1u, a2u;
      a1u.u = af0[base + mt * 16];
      a2u.u = af1[base + mt * 16];
      acc[mt] = __builtin_amdgcn_mfma_f32_16x16x32_bf16(a1u.v, b1u.v, acc[mt], 0, 0, 0);
      acc[mt] = __builtin_amdgcn_mfma_f32_16x16x32_bf16(a2u.v, b2u.v, acc[mt], 0, 0, 0);
    }
  }
  #pragma unroll
  for (int mt = 0; mt < 4; mt++)
    #pragma unroll
    for (int i = 0; i < 4; i++) {
      int m = mt * 16 + quad * 4 + i;
      splitbuf[((size_t)by * 64 + m) * IMG + n] = acc[mt][i];
    }
}

// ---------------- setup: pass-A partition scatter || prep || A-frag pack || goff --------

__global__ __launch_bounds__(256) void setup_fused(
    const int* __restrict__ row, const int* __restrict__ col,
    const float* __restrict__ ew, int* __restrict__ gbase, int2* __restrict__ pedge,
    const float* __restrict__ emb, const float* __restrict__ W1, float* __restrict__ embW,
    const float* __restrict__ W2, const float* __restrict__ W3,
    uint* __restrict__ Wbf2, uint* __restrict__ Wbf3,
    const float* __restrict__ images, uint4* __restrict__ AF,
    const int* __restrict__ batch, int* __restrict__ goff) {
  __shared__ int sh[2 * PART];  // hist | lbase
  int b = blockIdx.x;
  if (b < PABLK) {
    // pass A: 4 edges/thread; LDS histogram over 196 partitions; one padded global
    // returning atomic per (block, partition); scatter to partition regions.
    int* hist = sh;
    int* lbase = sh + PART;
    int t = threadIdx.x;
    for (int i = t; i < 2 * PART; i += 256) sh[i] = 0;
    __syncthreads();
    int e0 = b * 1024 + t * 4;
    int4 c4, r4;
    float4 w4;
    int pt0 = 0, pt1 = 0, pt2 = 0, pt3 = 0;
    int s0 = 0, s1 = 0, s2 = 0, s3 = 0;
    bool act = e0 < NE;  // NE % 4 == 0: active threads have full vectors
    if (act) {
      c4 = *(const int4*)(col + e0);
      r4 = *(const int4*)(row + e0);
      w4 = *(const float4*)(ew + e0);
      pt0 = c4.x >> 8; pt1 = c4.y >> 8; pt2 = c4.z >> 8; pt3 = c4.w >> 8;
      s0 = atomicAdd(&hist[pt0], 1);
      s1 = atomicAdd(&hist[pt1], 1);
      s2 = atomicAdd(&hist[pt2], 1);
      s3 = atomicAdd(&hist[pt3], 1);
    }
    __syncthreads();
    for (int i = t; i < PART; i += 256) {
      int c = hist[i];
      lbase[i] = c ? atomicAdd(&gbase[i * GSTRIDE], c) : 0;
    }
    __syncthreads();
    if (act) {
      int i0 = lbase[pt0] + s0;
      int i1 = lbase[pt1] + s1;
      int i2 = lbase[pt2] + s2;
      int i3 = lbase[pt3] + s3;
      if (i0 < PCAP)
        pedge[(size_t)pt0 * PCAP + i0] = make_int2(r4.x | ((c4.x & 255) << 17),
                                                   __float_as_int(w4.x));
      if (i1 < PCAP)
        pedge[(size_t)pt1 * PCAP + i1] = make_int2(r4.y | ((c4.y & 255) << 17),
                                                   __float_as_int(w4.y));
      if (i2 < PCAP)
        pedge[(size_t)pt2 * PCAP + i2] = make_int2(r4.z | ((c4.z & 255) << 17),
                                                   __float_as_int(w4.z));
      if (i3 < PCAP)
        pedge[(size_t)pt3 * PCAP + i3] = make_int2(r4.w | ((c4.w & 255) << 17),
                                                   __float_as_int(w4.w));
    }
  } else if (b < PABLK + PBLK) {
    int tid = (b - PABLK) * 256 + threadIdx.x;
    if (tid < NT * D) {
      // embW1 = emb @ W1^T (30x128)
      int tt = tid >> 7, nn2 = tid & 127;
      const float* ep = emb + (size_t)tt * D;
      const float* wp = W1 + (size_t)nn2 * D;
      float acc = 0.f;
      for (int k = 0; k < D; k += 4) {
        float4 evv = *(const float4*)(ep + k);
        float4 wvv = *(const float4*)(wp + k);
        acc += evv.x * wvv.x + evv.y * wvv.y + evv.z * wvv.z + evv.w * wvv.w;
      }
      embW[tid] = acc;
    } else if (tid < NT * D + D * 64) {
      int j = tid - NT * D;
      float2 v = ((const float2*)W2)[j];
      Wbf2[j] = pack2bf(v.x, v.y);
    } else {
      int j = tid - NT * D - D * 64;
      float2 v = ((const float2*)W3)[j];
      Wbf3[j] = pack2bf(v.x, v.y);
    }
  } else if (b < PABLK + PBLK + AFBLK) {
    // A-fragment pre-pack: AF[h][(by*4+ss)*4+quad][m] = bf16x8 of images[m][g*16+8h..]
    // with g = by*16 + ss*4 + quad. Writes coalesced (consecutive m per lane).
    int tid2 = (b - PABLK - PBLK) * 256 + threadIdx.x;  // 0..16383
    int m = tid2 & 63;
    int oo = tid2 >> 6;  // (by*4+ss)*4+quad
    int quad = oo & 3, ss = (oo >> 2) & 3, byy = oo >> 4;
    int k = (byy * 16 + ss * 4 + quad) << 4;
    const float* ap = images + (size_t)m * IMG + k;
    float4 a0_ = *(const float4*)(ap);
    float4 a1_ = *(const float4*)(ap + 4);
    float4 a2_ = *(const float4*)(ap + 8);
    float4 a3_ = *(const float4*)(ap + 12);
    uint4 h0, h1;
    h0.x = pack2bf(a0_.x, a0_.y);
    h0.y = pack2bf(a0_.z, a0_.w);
    h0.z = pack2bf(a1_.x, a1_.y);
    h0.w = pack2bf(a1_.z, a1_.w);
    h1.x = pack2bf(a2_.x, a2_.y);
    h1.y = pack2bf(a2_.z, a2_.w);
    h1.z = pack2bf(a3_.x, a3_.y);
    h1.w = pack2bf(a3_.z, a3_.w);
    AF[tid2] = h0;
    AF[AFPLANE + tid2] = h1;
  } else {
    int g = threadIdx.x;
    if (g <= NG) {
      int lo = 0, hi = NN;
      while (lo < hi) {
        int mid = (lo + hi) >> 1;
        if (batch[mid] < g) lo = mid + 1; else hi = mid;
      }
      goff[g] = lo;
    }
  }
}

// ---------------- img GEMM (long blocks first) || pass-B bucket build -------------------

__global__ __launch_bounds__(256) void bucket_plus_img(const int* __restrict__ gbase,
                                                       const int2* __restrict__ pedge,
                                                       const int* __restrict__ types,
                                                       int2* __restrict__ ebuf,
                                                       int* __restrict__ cnt,
                                                       float* __restrict__ dis,
                                                       const uint4* __restrict__ AF,
                                                       const float* __restrict__ Wimg,
                                                       float* __restrict__ splitbuf) {
  __shared__ int lcnt[256];
  __shared__ float ldeg[256];
  int b = blockIdx.x;
  if (b < IMGALL) {
    img_mfma_body(AF, Wimg, splitbuf, b & 63, b >> 6);
  } else {
    int t = threadIdx.x;
    lcnt[t] = 0;
    ldeg[t] = 0.f;
    __syncthreads();
    int p = b - IMGALL;
    int total = min(gbase[p * GSTRIDE], PCAP);
    const int2* src = pedge + (size_t)p * PCAP;
    for (int i = t; i < total; i += 256) {
      int2 rec = src[i];
      int nl = (rec.x >> 17) & 255;
      int sv = rec.x & SRCMASK;
      int s = atomicAdd(&lcnt[nl], 1);
      atomicAdd(&ldeg[nl], __int_as_float(rec.y));
      if (s < CAP)
        ebuf[(size_t)(p * 256 + nl) * CAP + s] = make_int2(sv | (types[sv] << 17), rec.y);
    }
    __syncthreads();
    int node = p * 256 + t;
    if (node < NN) {
      cnt[node] = lcnt[t];
      dis[node] = 1.0f / sqrtf(ldeg[t] + 1.0f);
    }
  }
}

// ---------------- layer 1: X1 = relu(sum_e norm*embW[type[src]] + dis^2*embW[type] + b1) --
// type comes baked in the record (rec.x >> 17): no per-edge types[] gather.

__global__ __launch_bounds__(512) void lay1_fused(const int* __restrict__ cnt,
                                                  const int2* __restrict__ ebuf,
                                                  const float* __restrict__ dis,
                                                  const int* __restrict__ types,
                                                  const float* __restrict__ embW,
                                                  const float* __restrict__ b1,
                                                  uint* __restrict__ outbf) {
  __shared__ float sE[NT * D];  // 15360 floats
  __shared__ float sB[D];
  int t = threadIdx.x;
  for (int i = t; i < NT * D; i += 512) sE[i] = embW[i];
  if (t < D) sB[t] = b1[t];
  __syncthreads();
  int wave = t >> 6, lane = t & 63;
  #pragma unroll
  for (int r = 0; r < 4; r++) {
    int node = blockIdx.x * 32 + wave * 4 + r;
    if (node >= NN) continue;
    float ax = sB[2 * lane], ay = sB[2 * lane + 1];
    int n = min(cnt[node], CAP);
    int nc = (n + 7) >> 3;
    const int2* eb = ebuf + (size_t)node * CAP;
    float disc = dis[node];
    for (int c = 0; c < nc; c++) {
      const int2* ep = eb + (c << 3);
      int4 q0 = *(const int4*)(ep + 0);
      int4 q1 = *(const int4*)(ep + 2);
      int4 q2 = *(const int4*)(ep + 4);
      int4 q3 = *(const int4*)(ep + 6);
      int t0 = q0.x >> 17, t1 = q0.z >> 17, t2 = q1.x >> 17, t3 = q1.z >> 17;
      int t4 = q2.x >> 17, t5 = q2.z >> 17, t6 = q3.x >> 17, t7 = q3.z >> 17;
      float m0 = dis[q0.x & SRCMASK] * __int_as_float(q0.y) * disc;
      float m1 = dis[q0.z & SRCMASK] * __int_as_float(q0.w) * disc;
      float m2 = dis[q1.x & SRCMASK] * __int_as_float(q1.y) * disc;
      float m3 = dis[q1.z & SRCMASK] * __int_as_float(q1.w) * disc;
      float m4 = dis[q2.x & SRCMASK] * __int_as_float(q2.y) * disc;
      float m5 = dis[q2.z & SRCMASK] * __int_as_float(q2.w) * disc;
      float m6 = dis[q3.x & SRCMASK] * __int_as_float(q3.y) * disc;
      float m7 = dis[q3.z & SRCMASK] * __int_as_float(q3.w) * disc;
      float2 e0 = *(const float2*)&sE[t0 * D + 2 * lane];
      float2 e1 = *(const float2*)&sE[t1 * D + 2 * lane];
      float2 e2 = *(const float2*)&sE[t2 * D + 2 * lane];
      float2 e3 = *(const float2*)&sE[t3 * D + 2 * lane];
      float2 e4 = *(const float2*)&sE[t4 * D + 2 * lane];
      float2 e5 = *(const float2*)&sE[t5 * D + 2 * lane];
      float2 e6 = *(const float2*)&sE[t6 * D + 2 * lane];
      float2 e7 = *(const float2*)&sE[t7 * D + 2 * lane];
      ax = fmaf(m0, e0.x, ax); ay = fmaf(m0, e0.y, ay);
      ax = fmaf(m1, e1.x, ax); ay = fmaf(m1, e1.y, ay);
      ax = fmaf(m2, e2.x, ax); ay = fmaf(m2, e2.y, ay);
      ax = fmaf(m3, e3.x, ax); ay = fmaf(m3, e3.y, ay);
      ax = fmaf(m4, e4.x, ax); ay = fmaf(m4, e4.y, ay);
      ax = fmaf(m5, e5.x, ax); ay = fmaf(m5, e5.y, ay);
      ax = fmaf(m6, e6.x, ax); ay = fmaf(m6, e6.y, ay);
      ax = fmaf(m7, e7.x, ax); ay = fmaf(m7, e7.y, ay);
    }
    float dd = disc * disc;
    float2 es = *(const float2*)&sE[types[node] * D + 2 * lane];
    ax = fmaf(dd, es.x, ax);
    ay = fmaf(dd, es.y, ay);
    ax = fmaxf(ax, 0.f);
    ay = fmaxf(ay, 0.f);
    outbf[(size_t)node * 64 + lane] = pack2bf(ax, ay);
  }
}

// ---------------- node GEMM via MFMA: xw = X @ W^T (bf16 row-major in/out) ----------------

__device__ __forceinline__ void node_gemm_body(const uint* __restrict__ Abf,
                                               const uint* __restrict__ Wbf,
                                               uint* __restrict__ outbf, int bx,
                                               ushort* __restrict__ tile) {
  int w = threadIdx.x >> 6, lane = threadIdx.x & 63;
  int quad = lane >> 4;
  int m0 = bx * 64 + w * 16;
  int mrow = m0 + (lane & 15);
  int arow = (mrow < NN) ? mrow : 0;
  uint4 afr[4];
  #pragma unroll
  for (int ks = 0; ks < 4; ks++)
    afr[ks] = *(const uint4*)(Abf + (size_t)arow * 64 + ks * 16 + quad * 4);
  f32x4 acc[8] = {};
  #pragma unroll
  for (int nt = 0; nt < 8; nt++) {
    int n = nt * 16 + (lane & 15);
    #pragma unroll
    for (int ks = 0; ks < 4; ks++) {
      union { uint4 u; bf16x8 v; } au, bu;
      au.u = afr[ks];
      bu.u = *(const uint4*)(Wbf + (size_t)n * 64 + ks * 16 + quad * 4);
      acc[nt] = __builtin_amdgcn_mfma_f32_16x16x32_bf16(au.v, bu.v, acc[nt], 0, 0, 0);
    }
  }
  ushort* tw = tile + w * 16 * 136;
  #pragma unroll
  for (int nt = 0; nt < 8; nt++)
    #pragma unroll
    for (int i = 0; i < 4; i++)
      tw[(quad * 4 + i) * 136 + nt * 16 + (lane & 15)] = (ushort)bf16rne(acc[nt][i]);
  __builtin_amdgcn_s_waitcnt(0);  // wave-local LDS ordering (per-wave tile)
  #pragma unroll
  for (int rep = 0; rep < 4; rep++) {
    int r = rep * 4 + quad;
    int j = lane & 15;
    int node = m0 + r;
    if (node < NN) {
      uint4 v = *(const uint4*)&tw[r * 136 + j * 8];
      *(uint4*)(outbf + (size_t)node * 64 + j * 4) = v;
    }
  }
}

// ---------------- aggregation body: 2 nodes/wave, dense 16-edge chunks -------------------

#define GA(k, s_) uint2 u##k = xw2[(size_t)(s_) * 32 + fl];
#define FA(k, m_) a0 = fmaf(m_, bflo(u##k.x), a0); a1 = fmaf(m_, bfhi(u##k.x), a1); \
                  a2 = fmaf(m_, bflo(u##k.y), a2); a3 = fmaf(m_, bfhi(u##k.y), a3);

__device__ __forceinline__ void aggregate2_body(const uint* __restrict__ xw,
                                                const int* __restrict__ cnt,
                                                const int2* __restrict__ ebuf,
                                                const float* __restrict__ dis,
                                                const float* __restrict__ bias, int relu,
                                                uint* __restrict__ outbf, int blk) {
  const uint2* xw2 = (const uint2*)xw;
  int wave = threadIdx.x >> 6;
  int lane = threadIdx.x & 63;
  int half = lane >> 5;
  int fl = lane & 31;  // uint2 index within row
  int node = (blk * 4 + wave) * 2 + half;
  if (node >= NN) return;
  float a0 = 0.f, a1 = 0.f, a2 = 0.f, a3 = 0.f;
  int n = min(cnt[node], CAP);
  int nc = (n + 15) >> 4;  // dense 16-edge chunks (CAP = 48 = 3*16)
  const int2* eb = ebuf + (size_t)node * CAP;
  float disc = dis[node];
  for (int c = 0; c < nc; c++) {
    const int2* ep = eb + (c << 4);
    int4 r0 = *(const int4*)(ep + 0);
    int4 r1 = *(const int4*)(ep + 2);
    int4 r2 = *(const int4*)(ep + 4);
    int4 r3 = *(const int4*)(ep + 6);
    int4 r4 = *(const int4*)(ep + 8);
    int4 r5 = *(const int4*)(ep + 10);
    int4 r6 = *(const int4*)(ep + 12);
    int4 r7 = *(const int4*)(ep + 14);
    int s0 = r0.x & SRCMASK, s1 = r0.z & SRCMASK, s2 = r1.x & SRCMASK, s3 = r1.z & SRCMASK;
    int s4 = r2.x & SRCMASK, s5 = r2.z & SRCMASK, s6 = r3.x & SRCMASK, s7 = r3.z & SRCMASK;
    int s8 = r4.x & SRCMASK, s9 = r4.z & SRCMASK, s10 = r5.x & SRCMASK, s11 = r5.z & SRCMASK;
    int s12 = r6.x & SRCMASK, s13 = r6.z & SRCMASK, s14 = r7.x & SRCMASK, s15 = r7.z & SRCMASK;
    GA(0, s0)  GA(1, s1)  GA(2, s2)  GA(3, s3)
    GA(4, s4)  GA(5, s5)  GA(6, s6)  GA(7, s7)
    GA(8, s8)  GA(9, s9)  GA(10, s10) GA(11, s11)
    GA(12, s12) GA(13, s13) GA(14, s14) GA(15, s15)
    float m0 = dis[s0] * __int_as_float(r0.y) * disc;
    float m1 = dis[s1] * __int_as_float(r0.w) * disc;
    float m2 = dis[s2] * __int_as_float(r1.y) * disc;
    float m3 = dis[s3] * __int_as_float(r1.w) * disc;
    float m4 = dis[s4] * __int_as_float(r2.y) * disc;
    float m5 = dis[s5] * __int_as_float(r2.w) * disc;
    float m6 = dis[s6] * __int_as_float(r3.y) * disc;
    float m7 = dis[s7] * __int_as_float(r3.w) * disc;
    float m8 = dis[s8] * __int_as_float(r4.y) * disc;
    float m9 = dis[s9] * __int_as_float(r4.w) * disc;
    float m10 = dis[s10] * __int_as_float(r5.y) * disc;
    float m11 = dis[s11] * __int_as_float(r5.w) * disc;
    float m12 = dis[s12] * __int_as_float(r6.y) * disc;
    float m13 = dis[s13] * __int_as_float(r6.w) * disc;
    float m14 = dis[s14] * __int_as_float(r7.y) * disc;
    float m15 = dis[s15] * __int_as_float(r7.w) * disc;
    FA(0, m0)  FA(1, m1)  FA(2, m2)  FA(3, m3)
    FA(4, m4)  FA(5, m5)  FA(6, m6)  FA(7, m7)
    FA(8, m8)  FA(9, m9)  FA(10, m10) FA(11, m11)
    FA(12, m12) FA(13, m13) FA(14, m14) FA(15, m15)
  }
  // self-loop
  float dd = disc * disc;
  {
    uint2 u = xw2[(size_t)node * 32 + fl];
    a0 = fmaf(dd, bflo(u.x), a0);
    a1 = fmaf(dd, bfhi(u.x), a1);
    a2 = fmaf(dd, bflo(u.y), a2);
    a3 = fmaf(dd, bfhi(u.y), a3);
  }
  float4 b = *(const float4*)(bias + 4 * fl);
  a0 += b.x; a1 += b.y; a2 += b.z; a3 += b.w;
  if (relu) {
    a0 = fmaxf(a0, 0.f);
    a1 = fmaxf(a1, 0.f);
    a2 = fmaxf(a2, 0.f);
    a3 = fmaxf(a3, 0.f);
  }
  uint2 o;
  o.x = pack2bf(a0, a1);
  o.y = pack2bf(a2, a3);
  ((uint2*)outbf)[(size_t)node * 32 + fl] = o;
}

// standalone aggregate (layer 2)
__global__ __launch_bounds__(256) void aggregate2(const uint* __restrict__ xw,
                                                  const int* __restrict__ cnt,
                                                  const int2* __restrict__ ebuf,
                                                  const float* __restrict__ dis,
                                                  const float* __restrict__ bias, int relu,
                                                  uint* __restrict__ outbf) {
  aggregate2_body(xw, cnt, ebuf, dis, bias, relu, outbf, blockIdx.x);
}

// ---------------- small-M GEMM body: bias folded into by==0; out pre-zeroed ------------

__device__ __forceinline__ void gemm64_body(const float* __restrict__ A, int lda,
                                            const float* __restrict__ W,
                                            const float* __restrict__ bias,
                                            float* __restrict__ out, int N, int K,
                                            int kChunk, int bx, int by,
                                            float (*xs)[68], float (*ws)[68]) {
  int t = threadIdx.x;
  int n0 = bx * 64;
  int k0 = by * kChunk;
  int kEnd = min(K, k0 + kChunk);
  int tn = t & 15;
  int tm = t >> 4;
  float acc[4][4] = {};
  if (by == 0) {
    #pragma unroll
    for (int ni = 0; ni < 4; ni++) {
      float bv = bias[n0 + tn * 4 + ni];
      #pragma unroll
      for (int mi = 0; mi < 4; mi++) acc[mi][ni] = bv;
    }
  }
  for (int kt = k0; kt < kEnd; kt += 16) {
    int kc = (t & 3) * 4;
    int rr = t >> 2;
    float4 va = *(const float4*)(A + (size_t)rr * lda + kt + kc);
    xs[kc + 0][rr] = va.x; xs[kc + 1][rr] = va.y; xs[kc + 2][rr] = va.z; xs[kc + 3][rr] = va.w;
    float4 vw = *(const float4*)(W + (size_t)(n0 + rr) * K + kt + kc);
    ws[kc + 0][rr] = vw.x; ws[kc + 1][rr] = vw.y; ws[kc + 2][rr] = vw.z; ws[kc + 3][rr] = vw.w;
    __syncthreads();
    #pragma unroll
    for (int k = 0; k < 16; k++) {
      float4 xv = *(const float4*)&xs[k][tm * 4];
      float4 wv = *(const float4*)&ws[k][tn * 4];
      float xm[4] = {xv.x, xv.y, xv.z, xv.w};
      float wn[4] = {wv.x, wv.y, wv.z, wv.w};
      #pragma unroll
      for (int mi = 0; mi < 4; mi++)
        #pragma unroll
        for (int ni = 0; ni < 4; ni++)
          acc[mi][ni] = fmaf(xm[mi], wn[ni], acc[mi][ni]);
    }
    __syncthreads();
  }
  #pragma unroll
  for (int mi = 0; mi < 4; mi++)
    #pragma unroll
    for (int ni = 0; ni < 4; ni++)
      atomicAdd(&out[(size_t)(tm * 4 + mi) * N + n0 + tn * 4 + ni], acc[mi][ni]);
}

// fused: img split-k reduce -> xcat (first) || node GEMM (W2)
__global__ __launch_bounds__(256) void gemm2_plus_imgred(const uint* __restrict__ bufX,
                                                         const uint* __restrict__ wbf2,
                                                         uint* __restrict__ bufB,
                                                         const float* __restrict__ splitbuf,
                                                         const float* __restrict__ b_img,
                                                         float* __restrict__ xcat) {
  __shared__ ushort tile[4 * 16 * 136];
  int b = blockIdx.x;
  if (b < IREDBLK) {
    int idx = b * 256 + threadIdx.x;
    float acc = b_img[idx & (IMG - 1)];
    #pragma unroll
    for (int s = 0; s < KSPLIT; s++) acc += splitbuf[(size_t)s * 64 * IMG + idx];
    xcat[(size_t)(idx >> 12) * (IMG + D) + (idx & (IMG - 1))] = acc;
  } else {
    node_gemm_body(bufX, wbf2, bufB, b - IREDBLK, tile);
  }
}

// fused: oi-GEMM (xi ready since imgred) first || node GEMM (W3); LDS aliased
__global__ __launch_bounds__(256) void gemm3_plus_oi(const uint* __restrict__ bufX,
                                                     const uint* __restrict__ wbf3,
                                                     uint* __restrict__ bufB,
                                                     const float* __restrict__ xcat,
                                                     const float* __restrict__ Wi,
                                                     const float* __restrict__ bi,
                                                     float* __restrict__ oi_raw) {
  __shared__ __align__(16) char smem[4 * 16 * 136 * 2];  // 17408 B, aliased
  int b = blockIdx.x;
  if (b < 64) {
    float (*xs)[68] = (float(*)[68])smem;
    float (*ws)[68] = (float(*)[68])(smem + 16 * 68 * 4);
    gemm64_body(xcat, IMG + D, Wi, bi, oi_raw, D, IMG, 128, b & 1, b >> 1, xs, ws);
  } else {
    node_gemm_body(bufX, wbf3, bufB, b - 64, (ushort*)smem);
  }
}

// fused: oc-GEMM k<4096 part (xi region) first || aggregate layer 3
__global__ __launch_bounds__(256) void agg3_plus_ocmain(const uint* __restrict__ bufB,
                                                        const int* __restrict__ cnt,
                                                        const int2* __restrict__ ebuf,
                                                        const float* __restrict__ dis,
                                                        const float* __restrict__ b3,
                                                        uint* __restrict__ bufX,
                                                        const float* __restrict__ xcat,
                                                        const float* __restrict__ Wc,
                                                        const float* __restrict__ bc,
                                                        float* __restrict__ oc_raw) {
  __shared__ float xs[16][68];
  __shared__ float ws[16][68];
  int b = blockIdx.x;
  if (b < 64) {
    gemm64_body(xcat, IMG + D, Wc, bc, oc_raw, D, IMG + D, 128, b & 1, b >> 1, xs, ws);
  } else {
    aggregate2_body(bufB, cnt, ebuf, dis, b3, 0, bufX, b - 64);
  }
}

// ---------------- pooling: scaled atomicAdd into xcat (32 chunks/graph) ----------------

__global__ __launch_bounds__(64) void pool_bf(const uint* __restrict__ xb,
                                              const int* __restrict__ goff,
                                              float* __restrict__ xcat) {
  int g = blockIdx.x >> 5;
  int chunk = blockIdx.x & 31;
  int fl = threadIdx.x;  // uint index within row
  int s = goff[g], e = goff[g + 1];
  float inv = 1.0f / fmaxf((float)(e - s), 1.0f);
  float ax = 0.f, ay = 0.f;
  for (int i = s + chunk; i < e; i += 32) {
    uint u = xb[(size_t)i * 64 + fl];
    ax += bflo(u);
    ay += bfhi(u);
  }
  atomicAdd(&xcat[(size_t)g * (IMG + D) + IMG + 2 * fl], ax * inv);
  atomicAdd(&xcat[(size_t)g * (IMG + D) + IMG + 2 * fl + 1], ay * inv);
}

// oc-GEMM tail: k in [4096, 4224) (pooled region), after pool
__global__ __launch_bounds__(256) void oc_tail(const float* __restrict__ xcat,
                                               const float* __restrict__ Wc,
                                               const float* __restrict__ bc,
                                               float* __restrict__ oc_raw) {
  __shared__ float xs[16][68];
  __shared__ float ws[16][68];
  gemm64_body(xcat, IMG + D, Wc, bc, oc_raw, D, IMG + D, 4096, blockIdx.x, 1, xs, ws);
}

__global__ __launch_bounds__(128) void normalize_rows(const float* __restrict__ oi_raw,
                                                      const float* __restrict__ oc_raw,
                                                      float* __restrict__ out) {
  int r = blockIdx.x;
  int t = threadIdx.x;
  const float* src = (r < 64) ? (oi_raw + r * D) : (oc_raw + (r - 64) * D);
  float v = src[t];
  __shared__ float red[128];
  red[t] = v * v;
  __syncthreads();
  for (int s = 64; s > 0; s >>= 1) {
    if (t < s) red[t] += red[t + s];
    __syncthreads();
  }
  out[r * D + t] = v / sqrtf(red[0]);
}

// ---------------- launch ----------------

extern "C" void kernel_launch(void* const* d_in, const int* in_sizes, int n_in,
                              void* d_out, int out_size, void* d_ws, size_t ws_size,
                              hipStream_t stream) {
  const float* images = (const float*)d_in[0];
  const int* node_types = (const int*)d_in[1];
  const int* erow = (const int*)d_in[2];
  const int* ecol = erow + NE;
  const float* eattr = (const float*)d_in[3];
  const int* batch = (const int*)d_in[4];
  const float* emb = (const float*)d_in[5];
  const float* W_img = (const float*)d_in[6];
  const float* b_img = (const float*)d_in[7];
  const float* W1 = (const float*)d_in[8];
  const float* b1 = (const float*)d_in[9];
  const float* W2 = (const float*)d_in[10];
  const float* b2 = (const float*)d_in[11];
  const float* W3 = (const float*)d_in[12];
  const float* b3 = (const float*)d_in[13];
  const float* Wi = (const float*)d_in[14];
  const float* bi = (const float*)d_in[15];
  const float* Wc = (const float*)d_in[16];
  const float* bc = (const float*)d_in[17];
  float* out = (float*)d_out;

  char* w = (char*)d_ws;
  auto alloc = [&](size_t bytes) -> void* {
    void* p = (void*)w;
    w += (bytes + 511) & ~(size_t)511;
    return p;
  };
  // zeroed region first: gbase(padded) + xcat + oi_raw + oc_raw + ebuf (~20.4 MB)
  int* gbase = (int*)alloc((size_t)PART * GSTRIDE * 4);  // 1 counter / 64B line
  float* xcat = (float*)alloc((size_t)64 * (IMG + D) * 4);
  float* oi_raw = (float*)alloc(64 * D * 4);
  float* oc_raw = (float*)alloc(64 * D * 4);
  int2* ebuf = (int2*)alloc((size_t)NN * CAP * 8);  // 19.2 MB zero-padded buckets
  size_t zero_bytes = (size_t)(w - (char*)d_ws);
  int* cnt = (int*)alloc((size_t)NN * 4);  // fully written by bucket_build
  int* goff = (int*)alloc((NG + 1) * 4);
  float* dis = (float*)alloc(NN * 4);
  float* embW1 = (float*)alloc(NT * D * 4);
  uint* wbf2 = (uint*)alloc(D * 64 * 4);
  uint* wbf3 = (uint*)alloc(D * 64 * 4);
  int2* pedge = (int2*)alloc((size_t)PART * PCAP * 8);  // 9.6 MB partition regions
  uint4* AF = (uint4*)alloc((size_t)2 * AFPLANE * 16);  // 512 KB A fragments
  uint* bufX = (uint*)alloc((size_t)NN * D * 2);  // X bf16 rows
  uint* bufB = (uint*)alloc((size_t)NN * D * 2);  // xw bf16 rows
  float* splitbuf = (float*)alloc((size_t)KSPLIT * 64 * IMG * 4);

  hipMemsetAsync(d_ws, 0, zero_bytes, stream);

  // pass-A partition scatter || prep || A-fragment pack || graph bounds
  setup_fused<<<PABLK + PBLK + AFBLK + 1, 256, 0, stream>>>(
      erow, ecol, eattr, gbase, pedge, emb, W1, embW1, W2, W3, wbf2, wbf3,
      images, AF, batch, goff);
  // img GEMM (16 k-slices, long blocks first) || pass-B bucket build
  bucket_plus_img<<<IMGALL + PART, 256, 0, stream>>>(gbase, pedge, node_types, ebuf,
                                                     cnt, dis, AF, W_img, splitbuf);
  // layer 1 (type-collapsed aggregation)
  lay1_fused<<<(NN + 31) / 32, 512, 0, stream>>>(cnt, ebuf, dis, node_types, embW1, b1, bufX);
  // img split-k reduce into xcat (first) || node GEMM W2
  gemm2_plus_imgred<<<IREDBLK + GBLK, 256, 0, stream>>>(bufX, wbf2, bufB, splitbuf, b_img,
                                                        xcat);
  // aggregate layer 2 (relu)
  aggregate2<<<AGGBLK, 256, 0, stream>>>(bufB, cnt, ebuf, dis, b2, 1, bufX);
  // oi = xi @ Wi^T + bi (first) || node GEMM W3
  gemm3_plus_oi<<<64 + GBLK, 256, 0, stream>>>(bufX, wbf3, bufB, xcat, Wi, bi, oi_raw);
  // oc k<4096 part (first) || aggregate layer 3 (no relu)
  agg3_plus_ocmain<<<64 + AGGBLK, 256, 0, stream>>>(bufB, cnt, ebuf, dis, b3, bufX,
                                                    xcat, Wc, bc, oc_raw);
  // mean-pool into xcat
  pool_bf<<<NG * 32, 64, 0, stream>>>(bufX, goff, xcat);
  // oc tail: k in [4096, 4224)
  oc_tail<<<2, 256, 0, stream>>>(xcat, Wc, bc, oc_raw);
  // row-normalize both heads
  normalize_rows<<<128, 128, 0, stream>>>(oi_raw, oc_raw, out);
}